// Round 1
// baseline (4988.991 us; speedup 1.0000x reference)
//
#include <hip/hip_runtime.h>
#include <math.h>

#define NN 8192
#define DD 2048
#define KK 256
#define NB 256   // persistent-loop blocks (1 per CU)
#define RPB 8    // G rows owned per block

// ---------- block reduce (256 threads, wave=64) ----------
__device__ __forceinline__ float blockReduceSum(float val, float* sdata) {
    for (int off = 32; off > 0; off >>= 1)
        val += __shfl_down(val, off, 64);
    int wid = threadIdx.x >> 6;
    int lane = threadIdx.x & 63;
    __syncthreads();
    if (lane == 0) sdata[wid] = val;
    __syncthreads();
    return sdata[0] + sdata[1] + sdata[2] + sdata[3];
}

// ---------- agent-scope (device-coherent) accessors: sc1 ops, NO cache-wide fences ----------
__device__ __forceinline__ float agload(const float* p) {
    return __hip_atomic_load(p, __ATOMIC_RELAXED, __HIP_MEMORY_SCOPE_AGENT);
}
__device__ __forceinline__ void agstore(float* p, float v) {
    __hip_atomic_store(p, v, __ATOMIC_RELAXED, __HIP_MEMORY_SCOPE_AGENT);
}

// ---------- sense-reversing grid barrier (relaxed atomics only; keeps G dirty in L2) ----------
// Safe because: __syncthreads() drains each wave's vmcnt (sc1 stores complete at the
// coherent point) before thread 0 arrives; consumers re-read shared vectors with sc1 loads.
__device__ __forceinline__ void gbar(unsigned* cnt, unsigned* genp, unsigned* gen_local) {
    __syncthreads();
    if (threadIdx.x == 0) {
        unsigned g0 = *gen_local;
        unsigned prev = __hip_atomic_fetch_add(cnt, 1u, __ATOMIC_RELAXED, __HIP_MEMORY_SCOPE_AGENT);
        if (prev == NB - 1u) {
            __hip_atomic_store(cnt, 0u, __ATOMIC_RELAXED, __HIP_MEMORY_SCOPE_AGENT);
            asm volatile("s_waitcnt vmcnt(0)" ::: "memory");  // reset lands before gen bump
            __hip_atomic_store(genp, g0 + 1u, __ATOMIC_RELAXED, __HIP_MEMORY_SCOPE_AGENT);
        } else {
            while (__hip_atomic_load(genp, __ATOMIC_RELAXED, __HIP_MEMORY_SCOPE_AGENT) == g0)
                __builtin_amdgcn_s_sleep(4);
        }
    }
    *gen_local = *gen_local + 1u;
    __syncthreads();
}

// ---------- V0 [D][K] -> V0T [K][D] ----------
__global__ void ktranspose(const float* __restrict__ V0, float* __restrict__ V0T) {
    __shared__ float tile[32][33];
    int bx = blockIdx.x;
    int by = blockIdx.y;
    int tx = threadIdx.x % 32;
    int ty = threadIdx.x / 32;
    for (int r = ty; r < 32; r += 8)
        tile[r][tx] = V0[(size_t)(bx * 32 + r) * KK + by * 32 + tx];
    __syncthreads();
    for (int r = ty; r < 32; r += 8)
        V0T[(size_t)(by * 32 + r) * DD + bx * 32 + tx] = tile[tx][r];
}

// ---------- d0[k] = ||V0[:,k]|| ----------
__global__ void kd0(const float* __restrict__ V0T, float* __restrict__ d0) {
    __shared__ float sdata[4];
    int k = blockIdx.x;
    float acc = 0.f;
    for (int j = threadIdx.x; j < DD; j += 256) {
        float v = V0T[(size_t)k * DD + j];
        acc += v * v;
    }
    float s = blockReduceSum(acc, sdata);
    if (threadIdx.x == 0) d0[k] = sqrtf(s);
}

// ---------- G = x^T x, triangle tiles + inline mirror ----------
__global__ void ksyrk(const float* __restrict__ x, float* __restrict__ G) {
    __shared__ float As[32][68];
    __shared__ float Bs[32][68];
    int t = blockIdx.x;
    int bj = (int)((sqrtf(8.0f * (float)t + 1.0f) - 1.0f) * 0.5f);
    while ((bj + 1) * (bj + 2) / 2 <= t) ++bj;
    while (bj * (bj + 1) / 2 > t) --bj;
    int bi = t - bj * (bj + 1) / 2;
    int a0 = bi * 64, b0 = bj * 64;
    int tid = threadIdx.x;
    int al = tid % 64;
    int nl0 = tid / 64;
    int tr = tid / 16, tc = tid % 16;
    float acc[4][4] = {};
    for (int n0 = 0; n0 < NN; n0 += 32) {
        for (int pass = 0; pass < 8; ++pass) {
            int nl = nl0 + pass * 4;
            As[nl][al] = x[(size_t)(n0 + nl) * DD + a0 + al];
            Bs[nl][al] = x[(size_t)(n0 + nl) * DD + b0 + al];
        }
        __syncthreads();
        for (int kk2 = 0; kk2 < 32; ++kk2) {
            float4 a4 = *(const float4*)&As[kk2][tr * 4];
            float4 b4 = *(const float4*)&Bs[kk2][tc * 4];
            float a[4] = {a4.x, a4.y, a4.z, a4.w};
            float b[4] = {b4.x, b4.y, b4.z, b4.w};
            for (int i = 0; i < 4; ++i)
                for (int j = 0; j < 4; ++j)
                    acc[i][j] += a[i] * b[j];
        }
        __syncthreads();
    }
    for (int i = 0; i < 4; ++i) {
        float4 o = make_float4(acc[i][0], acc[i][1], acc[i][2], acc[i][3]);
        *(float4*)&G[(size_t)(a0 + tr * 4 + i) * DD + b0 + tc * 4] = o;
    }
    if (bi != bj) {
        for (int i = 0; i < 4; ++i)
            for (int j = 0; j < 4; ++j)
                G[(size_t)(b0 + tc * 4 + j) * DD + a0 + tr * 4 + i] = acc[i][j];
    }
}

// ---------- legacy fallback kernels (used only if cooperative launch fails) ----------
__global__ void kmatvecG(const float* __restrict__ G, const float* __restrict__ v,
                         float* __restrict__ s) {
    __shared__ float vs[DD];
    int tid = threadIdx.x;
    for (int t2 = 0; t2 < 8; ++t2) vs[tid + t2 * 256] = v[tid + t2 * 256];
    __syncthreads();
    int wave = tid >> 6, lane = tid & 63;
    int row = blockIdx.x * 4 + wave;
    const float* Gr = G + (size_t)row * DD;
    float a = 0.f;
    for (int c = 0; c < 8; ++c) {
        int idx = lane * 4 + c * 256;
        float4 gq = *(const float4*)(Gr + idx);
        float4 vq = *(const float4*)(vs + idx);
        a += gq.x * vq.x + gq.y * vq.y + gq.z * vq.z + gq.w * vq.w;
    }
    for (int off = 32; off > 0; off >>= 1) a += __shfl_down(a, off, 64);
    if (lane == 0) s[row] = a;
}

__global__ void kstep1(const float* __restrict__ G, const float* __restrict__ V0T,
                       const float* __restrict__ d0, const float* __restrict__ s,
                       float* __restrict__ g, float* __restrict__ Vn, int k) {
    __shared__ float u[DD];
    __shared__ float sdata[4];
    __shared__ float sinv;
    int tid = threadIdx.x;
    const float* v = V0T + (size_t)k * DD;
    float cf = 0.5f / d0[k];
    float acc = 0.f;
    for (int t2 = 0; t2 < 8; ++t2) {
        int j = tid + t2 * 256;
        float uj = 0.5f * v[j] + cf * s[j];
        u[j] = uj;
        acc += uj * uj;
    }
    float n2 = blockReduceSum(acc, sdata);
    if (tid == 0) sinv = 1.0f / sqrtf(n2);
    __syncthreads();
    float inv = sinv;
    if (blockIdx.x == 0) {
        for (int t2 = 0; t2 < 8; ++t2) {
            int j = tid + t2 * 256;
            Vn[(size_t)k * DD + j] = u[j] * inv;
        }
    }
    int wave = tid >> 6, lane = tid & 63;
    int row = blockIdx.x * 4 + wave;
    const float* Gr = G + (size_t)row * DD;
    float a = 0.f;
    for (int c = 0; c < 8; ++c) {
        int idx = lane * 4 + c * 256;
        float4 gq = *(const float4*)(Gr + idx);
        float4 uq = *(const float4*)(u + idx);
        a += gq.x * uq.x + gq.y * uq.y + gq.z * uq.z + gq.w * uq.w;
    }
    for (int off = 32; off > 0; off >>= 1) a += __shfl_down(a, off, 64);
    if (lane == 0) g[row] = a * inv;
}

__global__ void kstep2(float* __restrict__ G, const float* __restrict__ V0T,
                       const float* __restrict__ Vn, const float* __restrict__ g,
                       float* __restrict__ s_next, int k, int knext) {
    __shared__ float vn_s[DD];
    __shared__ float h_s[DD];
    __shared__ float w_s[DD];
    __shared__ float sdata[4];
    int tid = threadIdx.x;
    float acc = 0.f;
    for (int t2 = 0; t2 < 8; ++t2) {
        int j = tid + t2 * 256;
        float vnj = Vn[(size_t)k * DD + j];
        float gj = g[j];
        vn_s[j] = vnj;
        h_s[j] = gj;
        w_s[j] = V0T[(size_t)knext * DD + j];
        acc += vnj * gj;
    }
    float c = blockReduceSum(acc, sdata);
    for (int t2 = 0; t2 < 8; ++t2) {
        int j = tid + t2 * 256;
        h_s[j] -= c * vn_s[j];
    }
    __syncthreads();
    int wave = tid >> 6, lane = tid & 63;
    int row = blockIdx.x * 4 + wave;
    float vni = vn_s[row], gi = g[row];
    float* Gr = G + (size_t)row * DD;
    float a = 0.f;
    for (int cc = 0; cc < 8; ++cc) {
        int idx = lane * 4 + cc * 256;
        float4 Gq = *(float4*)(Gr + idx);
        float4 hq = *(const float4*)(h_s + idx);
        float4 vq = *(const float4*)(vn_s + idx);
        float4 wq = *(const float4*)(w_s + idx);
        Gq.x = Gq.x - vni * hq.x - gi * vq.x;
        Gq.y = Gq.y - vni * hq.y - gi * vq.y;
        Gq.z = Gq.z - vni * hq.z - gi * vq.z;
        Gq.w = Gq.w - vni * hq.w - gi * vq.w;
        a += Gq.x * wq.x + Gq.y * wq.y + Gq.z * wq.z + Gq.w * wq.w;
        *(float4*)(Gr + idx) = Gq;
    }
    for (int off = 32; off > 0; off >>= 1) a += __shfl_down(a, off, 64);
    if (lane == 0) s_next[row] = a;
}

// ---------- persistent cooperative loop kernel ----------
// 256 blocks x 256 threads; block b owns G rows [8b, 8b+8). Those rows are only ever
// touched by their owner, so they stay dirty in the local L1/L2 for the whole loop
// (no release fences are executed anywhere in this kernel). Cross-block traffic
// (s, g vectors) goes through relaxed agent-scope (sc1) atomics.
__global__ void __launch_bounds__(256) kloop(
    float* __restrict__ G, const float* __restrict__ V0T,
    const float* __restrict__ d0, float* __restrict__ Vn,
    float* __restrict__ gbuf, float* __restrict__ sbuf,
    unsigned* bar) {
    __shared__ float vn_s[DD];   // holds u during phase A, then vn
    __shared__ float gs[DD];
    __shared__ float vk_s[DD];
    __shared__ float red[4];
    const int tid = threadIdx.x;
    const int b = blockIdx.x;
    const int wave = tid >> 6, lane = tid & 63;
    const int r0 = b * RPB + wave;          // this wave's rows: r0 and r0+4
    unsigned gen = 0;
    unsigned* cnt = bar;
    unsigned* genp = bar + 32;              // separate cache line from counter

    float* Gr0 = G + (size_t)r0 * DD;
    float* Gr1 = G + (size_t)(r0 + 4) * DD;

    // ---- prologue: s0 = G v0 ----
    for (int t = 0; t < 8; ++t) { int j = tid + t * 256; vn_s[j] = V0T[j]; }
    __syncthreads();
    {
        float a0 = 0.f, a1 = 0.f;
        for (int c = 0; c < 8; ++c) {
            int idx = lane * 4 + c * 256;
            float4 vq = *(const float4*)(vn_s + idx);
            float4 g0 = *(const float4*)(Gr0 + idx);
            float4 g1 = *(const float4*)(Gr1 + idx);
            a0 += g0.x * vq.x + g0.y * vq.y + g0.z * vq.z + g0.w * vq.w;
            a1 += g1.x * vq.x + g1.y * vq.y + g1.z * vq.z + g1.w * vq.w;
        }
        for (int off = 32; off > 0; off >>= 1) {
            a0 += __shfl_down(a0, off, 64);
            a1 += __shfl_down(a1, off, 64);
        }
        if (lane == 0) { agstore(&sbuf[r0], a0); agstore(&sbuf[r0 + 4], a1); }
    }
    gbar(cnt, genp, &gen);

    for (int k = 0; k < KK; ++k) {
        // ---- phase A: u, norm, Vn[k]; g = (G_k u)*inv ----
        const float* vk = V0T + (size_t)k * DD;
        float cf = 0.5f / d0[k];
        float acc = 0.f;
        for (int t = 0; t < 8; ++t) {
            int j = tid + t * 256;
            float u = 0.5f * vk[j] + cf * agload(&sbuf[j]);
            vn_s[j] = u;
            acc += u * u;
        }
        float n2 = blockReduceSum(acc, red);   // internal syncs publish u to the block
        float inv = 1.0f / sqrtf(n2);
        if (b == 0) {
            for (int t = 0; t < 8; ++t) {
                int j = tid + t * 256;
                Vn[(size_t)k * DD + j] = vn_s[j] * inv;
            }
        }
        if (k == KK - 1) break;

        {
            float a0 = 0.f, a1 = 0.f;
            for (int c = 0; c < 8; ++c) {
                int idx = lane * 4 + c * 256;
                float4 vq = *(const float4*)(vn_s + idx);
                float4 g0 = *(const float4*)(Gr0 + idx);
                float4 g1 = *(const float4*)(Gr1 + idx);
                a0 += g0.x * vq.x + g0.y * vq.y + g0.z * vq.z + g0.w * vq.w;
                a1 += g1.x * vq.x + g1.y * vq.y + g1.z * vq.z + g1.w * vq.w;
            }
            for (int off = 32; off > 0; off >>= 1) {
                a0 += __shfl_down(a0, off, 64);
                a1 += __shfl_down(a1, off, 64);
            }
            if (lane == 0) { agstore(&gbuf[r0], a0 * inv); agstore(&gbuf[r0 + 4], a1 * inv); }
        }
        __syncthreads();                       // all waves done reading u
        for (int t = 0; t < 8; ++t) { int j = tid + t * 256; vn_s[j] *= inv; }
        gbar(cnt, genp, &gen);

        // ---- phase B: c = vn.g; G -= vn h^T + g vn^T; fused s_next = G' v_next ----
        const float* vkn = V0T + (size_t)(k + 1) * DD;
        float acc2 = 0.f;
        for (int t = 0; t < 8; ++t) {
            int j = tid + t * 256;
            float gj = agload(&gbuf[j]);
            gs[j] = gj;
            vk_s[j] = vkn[j];
            acc2 += gj * vn_s[j];
        }
        float c = blockReduceSum(acc2, red);   // internal syncs publish gs/vk_s
        {
            float vn0 = vn_s[r0], vn1 = vn_s[r0 + 4];
            float g0r = gs[r0], g1r = gs[r0 + 4];
            float a0 = 0.f, a1 = 0.f;
            for (int cc = 0; cc < 8; ++cc) {
                int idx = lane * 4 + cc * 256;
                float4 vq = *(const float4*)(vn_s + idx);
                float4 gq = *(const float4*)(gs + idx);
                float4 wq = *(const float4*)(vk_s + idx);
                float4 G0 = *(float4*)(Gr0 + idx);
                float4 G1 = *(float4*)(Gr1 + idx);
                float hx = gq.x - c * vq.x;
                float hy = gq.y - c * vq.y;
                float hz = gq.z - c * vq.z;
                float hw = gq.w - c * vq.w;
                G0.x = G0.x - vn0 * hx - g0r * vq.x;
                G0.y = G0.y - vn0 * hy - g0r * vq.y;
                G0.z = G0.z - vn0 * hz - g0r * vq.z;
                G0.w = G0.w - vn0 * hw - g0r * vq.w;
                G1.x = G1.x - vn1 * hx - g1r * vq.x;
                G1.y = G1.y - vn1 * hy - g1r * vq.y;
                G1.z = G1.z - vn1 * hz - g1r * vq.z;
                G1.w = G1.w - vn1 * hw - g1r * vq.w;
                a0 += G0.x * wq.x + G0.y * wq.y + G0.z * wq.z + G0.w * wq.w;
                a1 += G1.x * wq.x + G1.y * wq.y + G1.z * wq.z + G1.w * wq.w;
                *(float4*)(Gr0 + idx) = G0;
                *(float4*)(Gr1 + idx) = G1;
            }
            for (int off = 32; off > 0; off >>= 1) {
                a0 += __shfl_down(a0, off, 64);
                a1 += __shfl_down(a1, off, 64);
            }
            if (lane == 0) { agstore(&sbuf[r0], a0); agstore(&sbuf[r0 + 4], a1); }
        }
        gbar(cnt, genp, &gen);
    }
}

// ---------- out[N][K] = x . Vn^T ----------
__global__ void kout(const float* __restrict__ x, const float* __restrict__ Vn,
                     float* __restrict__ out) {
    __shared__ float As[32][68];
    __shared__ float Bs[32][68];
    int i0 = blockIdx.x * 64;
    int k0 = blockIdx.y * 64;
    int tid = threadIdx.x;
    int tr = tid / 16;
    int tc = tid % 16;
    float acc[4][4] = {};
    for (int j0 = 0; j0 < DD; j0 += 32) {
        int c = tid % 32;
        int r0 = tid / 32;
        for (int pass = 0; pass < 8; ++pass) {
            int rr = r0 + pass * 8;
            As[c][rr] = x[(size_t)(i0 + rr) * DD + j0 + c];
            Bs[c][rr] = Vn[(size_t)(k0 + rr) * DD + j0 + c];
        }
        __syncthreads();
        for (int kk = 0; kk < 32; ++kk) {
            float4 a4 = *(const float4*)&As[kk][tr * 4];
            float4 b4 = *(const float4*)&Bs[kk][tc * 4];
            float a[4] = {a4.x, a4.y, a4.z, a4.w};
            float b[4] = {b4.x, b4.y, b4.z, b4.w};
            for (int ar = 0; ar < 4; ++ar)
                for (int bc = 0; bc < 4; ++bc)
                    acc[ar][bc] += a[ar] * b[bc];
        }
        __syncthreads();
    }
    for (int ar = 0; ar < 4; ++ar) {
        float4 o = make_float4(acc[ar][0], acc[ar][1], acc[ar][2], acc[ar][3]);
        *(float4*)&out[(size_t)(i0 + tr * 4 + ar) * KK + k0 + tc * 4] = o;
    }
}

extern "C" void kernel_launch(void* const* d_in, const int* in_sizes, int n_in,
                              void* d_out, int out_size, void* d_ws, size_t ws_size,
                              hipStream_t stream) {
    const float* x  = (const float*)d_in[0];   // [N*D]
    const float* V0 = (const float*)d_in[1];   // [D*K]
    float* out = (float*)d_out;                // [N*K]

    float* G    = (float*)d_ws;                // D*D
    float* V0T  = G + (size_t)DD * DD;         // K*D
    float* Vn   = V0T + (size_t)KK * DD;       // K*D
    float* g    = Vn + (size_t)KK * DD;        // D
    float* sbuf = g + DD;                      // 2*D (coop path uses first D only)
    float* d0   = sbuf + 2 * DD;               // K
    // barrier words overlay sbuf's second half (unused by the coop path)
    unsigned* bar = (unsigned*)(sbuf + DD);    // [0]=counter, [32]=generation

    ktranspose<<<dim3(DD / 32, KK / 32), 256, 0, stream>>>(V0, V0T);
    kd0<<<KK, 256, 0, stream>>>(V0T, d0);
    ksyrk<<<528, 256, 0, stream>>>(x, G);

    hipMemsetAsync(bar, 0, 33 * sizeof(unsigned), stream);
    void* kargs[] = {(void*)&G, (void*)&V0T, (void*)&d0, (void*)&Vn,
                     (void*)&g, (void*)&sbuf, (void*)&bar};
    hipError_t cerr = hipLaunchCooperativeKernel(kloop, dim3(NB), dim3(256),
                                                 kargs, 0, stream);
    if (cerr != hipSuccess) {
        // fallback: original per-iteration launch loop
        kmatvecG<<<512, 256, 0, stream>>>(G, V0T, sbuf);
        for (int k = 0; k < KK; ++k) {
            float* s_cur = sbuf + (k & 1) * DD;
            float* s_nxt = sbuf + ((k + 1) & 1) * DD;
            kstep1<<<512, 256, 0, stream>>>(G, V0T, d0, s_cur, g, Vn, k);
            if (k < KK - 1)
                kstep2<<<512, 256, 0, stream>>>(G, V0T, Vn, g, s_nxt, k, k + 1);
        }
    }

    kout<<<dim3(NN / 64, KK / 64), 256, 0, stream>>>(x, Vn, out);
}

// Round 2
// 2872.054 us; speedup vs baseline: 1.7371x; 1.7371x over previous
//
#include <hip/hip_runtime.h>
#include <math.h>

#define NN 8192
#define DD 2048
#define KK 256
#define NB 256    // persistent blocks (1 per CU)
#define RPB 8     // G rows owned per block
#define NGRP 16   // barrier tree groups
#define GSZ 16    // blocks per group

// ---------- block reduce (256 threads, wave=64) — legacy kernels ----------
__device__ __forceinline__ float blockReduceSum(float val, float* sdata) {
    for (int off = 32; off > 0; off >>= 1)
        val += __shfl_down(val, off, 64);
    int wid = threadIdx.x >> 6;
    int lane = threadIdx.x & 63;
    __syncthreads();
    if (lane == 0) sdata[wid] = val;
    __syncthreads();
    return sdata[0] + sdata[1] + sdata[2] + sdata[3];
}

// ---------- agent-scope (device-coherent) accessors ----------
__device__ __forceinline__ float agload(const float* p) {
    return __hip_atomic_load(p, __ATOMIC_RELAXED, __HIP_MEMORY_SCOPE_AGENT);
}
__device__ __forceinline__ void agstore(float* p, float v) {
    __hip_atomic_store(p, v, __ATOMIC_RELAXED, __HIP_MEMORY_SCOPE_AGENT);
}

// ---------- two-level tree grid barrier (relaxed agent atomics only) ----------
// Arrival: 16-way atomics per group line + 16 at root (vs 256 serialized on one line).
// __syncthreads() before arrival drains vmcnt -> all this block's sc1/global stores done.
__device__ __forceinline__ void gbar2(unsigned* bar, int b, unsigned* gen_local) {
    __syncthreads();
    if (threadIdx.x == 0) {
        unsigned g0 = *gen_local;
        int grp = b >> 4;
        unsigned* gcnt = bar + (size_t)grp * 64;
        unsigned* ggen = bar + 1024 + (size_t)grp * 64;
        unsigned* rcnt = bar + 2048;
        unsigned* rgen = bar + 2112;
        unsigned prev = __hip_atomic_fetch_add(gcnt, 1u, __ATOMIC_RELAXED, __HIP_MEMORY_SCOPE_AGENT);
        if (prev == GSZ - 1u) {
            unsigned prevr = __hip_atomic_fetch_add(rcnt, 1u, __ATOMIC_RELAXED, __HIP_MEMORY_SCOPE_AGENT);
            if (prevr == NGRP - 1u) {
                __hip_atomic_store(rcnt, 0u, __ATOMIC_RELAXED, __HIP_MEMORY_SCOPE_AGENT);
                asm volatile("s_waitcnt vmcnt(0)" ::: "memory"); // reset lands first
                __hip_atomic_store(rgen, g0 + 1u, __ATOMIC_RELAXED, __HIP_MEMORY_SCOPE_AGENT);
            } else {
                while (__hip_atomic_load(rgen, __ATOMIC_RELAXED, __HIP_MEMORY_SCOPE_AGENT) == g0)
                    __builtin_amdgcn_s_sleep(1);
            }
            __hip_atomic_store(gcnt, 0u, __ATOMIC_RELAXED, __HIP_MEMORY_SCOPE_AGENT);
            asm volatile("s_waitcnt vmcnt(0)" ::: "memory");     // reset lands first
            __hip_atomic_store(ggen, g0 + 1u, __ATOMIC_RELAXED, __HIP_MEMORY_SCOPE_AGENT);
        } else {
            while (__hip_atomic_load(ggen, __ATOMIC_RELAXED, __HIP_MEMORY_SCOPE_AGENT) == g0)
                __builtin_amdgcn_s_sleep(1);
        }
    }
    *gen_local += 1u;
    __syncthreads();
}

// ---------- V0 [D][K] -> V0T [K][D] ----------
__global__ void ktranspose(const float* __restrict__ V0, float* __restrict__ V0T) {
    __shared__ float tile[32][33];
    int bx = blockIdx.x;
    int by = blockIdx.y;
    int tx = threadIdx.x % 32;
    int ty = threadIdx.x / 32;
    for (int r = ty; r < 32; r += 8)
        tile[r][tx] = V0[(size_t)(bx * 32 + r) * KK + by * 32 + tx];
    __syncthreads();
    for (int r = ty; r < 32; r += 8)
        V0T[(size_t)(by * 32 + r) * DD + bx * 32 + tx] = tile[tx][r];
}

// ---------- d0[k] = ||V0[:,k]|| ----------
__global__ void kd0(const float* __restrict__ V0T, float* __restrict__ d0) {
    __shared__ float sdata[4];
    int k = blockIdx.x;
    float acc = 0.f;
    for (int j = threadIdx.x; j < DD; j += 256) {
        float v = V0T[(size_t)k * DD + j];
        acc += v * v;
    }
    float s = blockReduceSum(acc, sdata);
    if (threadIdx.x == 0) d0[k] = sqrtf(s);
}

// ---------- G = x^T x, triangle tiles + inline mirror ----------
__global__ void ksyrk(const float* __restrict__ x, float* __restrict__ G) {
    __shared__ float As[32][68];
    __shared__ float Bs[32][68];
    int t = blockIdx.x;
    int bj = (int)((sqrtf(8.0f * (float)t + 1.0f) - 1.0f) * 0.5f);
    while ((bj + 1) * (bj + 2) / 2 <= t) ++bj;
    while (bj * (bj + 1) / 2 > t) --bj;
    int bi = t - bj * (bj + 1) / 2;
    int a0 = bi * 64, b0 = bj * 64;
    int tid = threadIdx.x;
    int al = tid % 64;
    int nl0 = tid / 64;
    int tr = tid / 16, tc = tid % 16;
    float acc[4][4] = {};
    for (int n0 = 0; n0 < NN; n0 += 32) {
        for (int pass = 0; pass < 8; ++pass) {
            int nl = nl0 + pass * 4;
            As[nl][al] = x[(size_t)(n0 + nl) * DD + a0 + al];
            Bs[nl][al] = x[(size_t)(n0 + nl) * DD + b0 + al];
        }
        __syncthreads();
        for (int kk2 = 0; kk2 < 32; ++kk2) {
            float4 a4 = *(const float4*)&As[kk2][tr * 4];
            float4 b4 = *(const float4*)&Bs[kk2][tc * 4];
            float a[4] = {a4.x, a4.y, a4.z, a4.w};
            float b[4] = {b4.x, b4.y, b4.z, b4.w};
            for (int i = 0; i < 4; ++i)
                for (int j = 0; j < 4; ++j)
                    acc[i][j] += a[i] * b[j];
        }
        __syncthreads();
    }
    for (int i = 0; i < 4; ++i) {
        float4 o = make_float4(acc[i][0], acc[i][1], acc[i][2], acc[i][3]);
        *(float4*)&G[(size_t)(a0 + tr * 4 + i) * DD + b0 + tc * 4] = o;
    }
    if (bi != bj) {
        for (int i = 0; i < 4; ++i)
            for (int j = 0; j < 4; ++j)
                G[(size_t)(b0 + tc * 4 + j) * DD + a0 + tr * 4 + i] = acc[i][j];
    }
}

// ---------- legacy fallback kernels (used only if cooperative launch fails) ----------
__global__ void kmatvecG(const float* __restrict__ G, const float* __restrict__ v,
                         float* __restrict__ s) {
    __shared__ float vs[DD];
    int tid = threadIdx.x;
    for (int t2 = 0; t2 < 8; ++t2) vs[tid + t2 * 256] = v[tid + t2 * 256];
    __syncthreads();
    int wave = tid >> 6, lane = tid & 63;
    int row = blockIdx.x * 4 + wave;
    const float* Gr = G + (size_t)row * DD;
    float a = 0.f;
    for (int c = 0; c < 8; ++c) {
        int idx = lane * 4 + c * 256;
        float4 gq = *(const float4*)(Gr + idx);
        float4 vq = *(const float4*)(vs + idx);
        a += gq.x * vq.x + gq.y * vq.y + gq.z * vq.z + gq.w * vq.w;
    }
    for (int off = 32; off > 0; off >>= 1) a += __shfl_down(a, off, 64);
    if (lane == 0) s[row] = a;
}

__global__ void kstep1(const float* __restrict__ G, const float* __restrict__ V0T,
                       const float* __restrict__ d0, const float* __restrict__ s,
                       float* __restrict__ g, float* __restrict__ Vn, int k) {
    __shared__ float u[DD];
    __shared__ float sdata[4];
    __shared__ float sinv;
    int tid = threadIdx.x;
    const float* v = V0T + (size_t)k * DD;
    float cf = 0.5f / d0[k];
    float acc = 0.f;
    for (int t2 = 0; t2 < 8; ++t2) {
        int j = tid + t2 * 256;
        float uj = 0.5f * v[j] + cf * s[j];
        u[j] = uj;
        acc += uj * uj;
    }
    float n2 = blockReduceSum(acc, sdata);
    if (tid == 0) sinv = 1.0f / sqrtf(n2);
    __syncthreads();
    float inv = sinv;
    if (blockIdx.x == 0) {
        for (int t2 = 0; t2 < 8; ++t2) {
            int j = tid + t2 * 256;
            Vn[(size_t)k * DD + j] = u[j] * inv;
        }
    }
    int wave = tid >> 6, lane = tid & 63;
    int row = blockIdx.x * 4 + wave;
    const float* Gr = G + (size_t)row * DD;
    float a = 0.f;
    for (int c = 0; c < 8; ++c) {
        int idx = lane * 4 + c * 256;
        float4 gq = *(const float4*)(Gr + idx);
        float4 uq = *(const float4*)(u + idx);
        a += gq.x * uq.x + gq.y * uq.y + gq.z * uq.z + gq.w * uq.w;
    }
    for (int off = 32; off > 0; off >>= 1) a += __shfl_down(a, off, 64);
    if (lane == 0) g[row] = a * inv;
}

__global__ void kstep2(float* __restrict__ G, const float* __restrict__ V0T,
                       const float* __restrict__ Vn, const float* __restrict__ g,
                       float* __restrict__ s_next, int k, int knext) {
    __shared__ float vn_s[DD];
    __shared__ float h_s[DD];
    __shared__ float w_s[DD];
    __shared__ float sdata[4];
    int tid = threadIdx.x;
    float acc = 0.f;
    for (int t2 = 0; t2 < 8; ++t2) {
        int j = tid + t2 * 256;
        float vnj = Vn[(size_t)k * DD + j];
        float gj = g[j];
        vn_s[j] = vnj;
        h_s[j] = gj;
        w_s[j] = V0T[(size_t)knext * DD + j];
        acc += vnj * gj;
    }
    float c = blockReduceSum(acc, sdata);
    for (int t2 = 0; t2 < 8; ++t2) {
        int j = tid + t2 * 256;
        h_s[j] -= c * vn_s[j];
    }
    __syncthreads();
    int wave = tid >> 6, lane = tid & 63;
    int row = blockIdx.x * 4 + wave;
    float vni = vn_s[row], gi = g[row];
    float* Gr = G + (size_t)row * DD;
    float a = 0.f;
    for (int cc = 0; cc < 8; ++cc) {
        int idx = lane * 4 + cc * 256;
        float4 Gq = *(float4*)(Gr + idx);
        float4 hq = *(const float4*)(h_s + idx);
        float4 vq = *(const float4*)(vn_s + idx);
        float4 wq = *(const float4*)(w_s + idx);
        Gq.x = Gq.x - vni * hq.x - gi * vq.x;
        Gq.y = Gq.y - vni * hq.y - gi * vq.y;
        Gq.z = Gq.z - vni * hq.z - gi * vq.z;
        Gq.w = Gq.w - vni * hq.w - gi * vq.w;
        a += Gq.x * wq.x + Gq.y * wq.y + Gq.z * wq.z + Gq.w * wq.w;
        *(float4*)(Gr + idx) = Gq;
    }
    for (int off = 32; off > 0; off >>= 1) a += __shfl_down(a, off, 64);
    if (lane == 0) s_next[row] = a;
}

// ---------- persistent cooperative loop: 1 barrier + 1 fused G sweep per iteration ----------
// Recurrences (G_k = matrix after k deflations; vn_k from phase k):
//   iteration k holds: vnp = vn_{k-1} (LDS), gbuf[p] = g_{k-1} = G_{k-1} vn_{k-1},
//                      wbuf[p] = w = G_{k-1} v_k           (p = k&1)
//   c   = vnp . g_{k-1}
//   s_k = w - (g.v_k - c*(vnp.v_k)) * vnp - (vnp.v_k) * g      [= G_k v_k]
//   u   = 0.5 v_k + (0.5/d0[k]) s_k ; vn_k = u/||u||
//   sweep own rows: G_r -= vnp[r]*g_{k-1} + (g_{k-1}[r]-c*vnp[r])*vnp   [G_{k-1} -> G_k]
//                   g_k[r] = G_k[r,:].vn_k ; w'[r] = G_k[r,:].v_{k+1}
//   one grid barrier.
__global__ void __launch_bounds__(1024, 4) kloop2(
    float* __restrict__ G, const float* __restrict__ V0T,
    const float* __restrict__ d0, float* __restrict__ Vn,
    float* __restrict__ gbuf, float* __restrict__ wbuf,
    unsigned* bar) {
    __shared__ float vbuf[2][DD];   // vn ping-pong (vnp / vnew)
    __shared__ float gs[DD];        // g_{k-1}
    __shared__ float vx[DD];        // v_{k+1} for the sweep's w-dot
    __shared__ float redA[16], redB[16], redC[16];
    __shared__ float partg[16], partw[16];
    const int tid = threadIdx.x;
    const int b = blockIdx.x;
    const int wave = tid >> 6, lane = tid & 63;
    const int rowi = wave >> 1;     // 0..7
    const int half = wave & 1;      // which half-row this wave covers
    const int row = b * RPB + rowi;
    float* Gr = G + (size_t)row * DD;
    unsigned gen = 0;

    // ---- prologue: vnp=0; w0 = G0 v0 ----
    vbuf[0][tid] = 0.f;
    vbuf[0][tid + 1024] = 0.f;
    vx[tid] = V0T[tid];
    vx[tid + 1024] = V0T[tid + 1024];
    __syncthreads();
    {
        float aw = 0.f;
        for (int c = 0; c < 4; ++c) {
            int idx = half * 1024 + lane * 4 + c * 256;
            float4 g4 = *(const float4*)(Gr + idx);
            float4 x4 = *(const float4*)(vx + idx);
            aw += g4.x * x4.x + g4.y * x4.y + g4.z * x4.z + g4.w * x4.w;
        }
        for (int off = 32; off > 0; off >>= 1) aw += __shfl_down(aw, off, 64);
        if (lane == 0) partw[wave] = aw;
    }
    __syncthreads();
    if (tid < RPB)
        agstore(&wbuf[b * RPB + tid], partw[2 * tid] + partw[2 * tid + 1]);
    gbar2(bar, b, &gen);

    for (int k = 0; k < KK; ++k) {
        const int p = k & 1;
        const float* vnp = vbuf[p];
        float* vnew = vbuf[p ^ 1];
        const float* gsrc = gbuf + (size_t)p * DD;
        const float* wsrc = wbuf + (size_t)p * DD;
        float* gdst = gbuf + (size_t)(p ^ 1) * DD;
        float* wdst = wbuf + (size_t)(p ^ 1) * DD;
        const float* vk = V0T + (size_t)k * DD;

        // ---- dots pass: c = vnp.g, gv = g.vk, bv = vnp.vk ----
        float vk0 = vk[tid], vk1 = vk[tid + 1024];
        float g0 = agload(&gsrc[tid]), g1 = agload(&gsrc[tid + 1024]);
        gs[tid] = g0;
        gs[tid + 1024] = g1;
        float vp0 = vnp[tid], vp1 = vnp[tid + 1024];
        float pc = vp0 * g0 + vp1 * g1;
        float pgv = g0 * vk0 + g1 * vk1;
        float pbv = vp0 * vk0 + vp1 * vk1;
        for (int off = 32; off > 0; off >>= 1) {
            pc += __shfl_down(pc, off, 64);
            pgv += __shfl_down(pgv, off, 64);
            pbv += __shfl_down(pbv, off, 64);
        }
        __syncthreads();
        if (lane == 0) { redA[wave] = pc; redB[wave] = pgv; redC[wave] = pbv; }
        __syncthreads();
        float c_s = 0.f, gv = 0.f, bv = 0.f;
        for (int i = 0; i < 16; ++i) { c_s += redA[i]; gv += redB[i]; bv += redC[i]; }
        float alpha = gv - c_s * bv;   // h . v_k
        float beta = bv;               // vnp . v_k

        // ---- u pass: s = w - alpha*vnp - beta*g ; u = 0.5 vk + cf*s ----
        float cf = 0.5f / d0[k];
        float w0 = agload(&wsrc[tid]), w1 = agload(&wsrc[tid + 1024]);
        float u0 = 0.5f * vk0 + cf * (w0 - alpha * vp0 - beta * g0);
        float u1 = 0.5f * vk1 + cf * (w1 - alpha * vp1 - beta * g1);
        float pn = u0 * u0 + u1 * u1;
        for (int off = 32; off > 0; off >>= 1) pn += __shfl_down(pn, off, 64);
        __syncthreads();               // all done reading redA/B/C
        if (lane == 0) redA[wave] = pn;
        __syncthreads();
        float n2 = 0.f;
        for (int i = 0; i < 16; ++i) n2 += redA[i];
        float inv = 1.0f / sqrtf(n2);

        if (b == 0) {
            Vn[(size_t)k * DD + tid] = u0 * inv;
            Vn[(size_t)k * DD + tid + 1024] = u1 * inv;
        }
        if (k == KK - 1) break;

        vnew[tid] = u0 * inv;
        vnew[tid + 1024] = u1 * inv;
        // load v_{k+1} for the sweep's w-dot
        const float* vkn = V0T + (size_t)(k + 1) * DD;
        vx[tid] = vkn[tid];
        vx[tid + 1024] = vkn[tid + 1024];
        __syncthreads();               // publish vnew, vx

        // ---- fused sweep: update own rows G_{k-1}->G_k, dot with vn_k and v_{k+1} ----
        {
            float a_r = vnp[row];
            float g_r = gs[row];
            float b_r = g_r - c_s * a_r;
            float ag = 0.f, aw = 0.f;
            for (int c = 0; c < 4; ++c) {
                int idx = half * 1024 + lane * 4 + c * 256;
                float4 G4 = *(float4*)(Gr + idx);
                float4 gq = *(const float4*)(gs + idx);
                float4 vq = *(const float4*)(vnp + idx);
                float4 nq = *(const float4*)(vnew + idx);
                float4 xq = *(const float4*)(vx + idx);
                G4.x -= a_r * gq.x + b_r * vq.x;
                G4.y -= a_r * gq.y + b_r * vq.y;
                G4.z -= a_r * gq.z + b_r * vq.z;
                G4.w -= a_r * gq.w + b_r * vq.w;
                ag += G4.x * nq.x + G4.y * nq.y + G4.z * nq.z + G4.w * nq.w;
                aw += G4.x * xq.x + G4.y * xq.y + G4.z * xq.z + G4.w * xq.w;
                *(float4*)(Gr + idx) = G4;
            }
            for (int off = 32; off > 0; off >>= 1) {
                ag += __shfl_down(ag, off, 64);
                aw += __shfl_down(aw, off, 64);
            }
            if (lane == 0) { partg[wave] = ag; partw[wave] = aw; }
        }
        __syncthreads();
        if (tid < RPB) {
            int r = b * RPB + tid;
            agstore(&gdst[r], partg[2 * tid] + partg[2 * tid + 1]);
            agstore(&wdst[r], partw[2 * tid] + partw[2 * tid + 1]);
        }
        gbar2(bar, b, &gen);
    }
}

// ---------- out[N][K] = x . Vn^T ----------
__global__ void kout(const float* __restrict__ x, const float* __restrict__ Vn,
                     float* __restrict__ out) {
    __shared__ float As[32][68];
    __shared__ float Bs[32][68];
    int i0 = blockIdx.x * 64;
    int k0 = blockIdx.y * 64;
    int tid = threadIdx.x;
    int tr = tid / 16;
    int tc = tid % 16;
    float acc[4][4] = {};
    for (int j0 = 0; j0 < DD; j0 += 32) {
        int c = tid % 32;
        int r0 = tid / 32;
        for (int pass = 0; pass < 8; ++pass) {
            int rr = r0 + pass * 8;
            As[c][rr] = x[(size_t)(i0 + rr) * DD + j0 + c];
            Bs[c][rr] = Vn[(size_t)(k0 + rr) * DD + j0 + c];
        }
        __syncthreads();
        for (int kk = 0; kk < 32; ++kk) {
            float4 a4 = *(const float4*)&As[kk][tr * 4];
            float4 b4 = *(const float4*)&Bs[kk][tc * 4];
            float a[4] = {a4.x, a4.y, a4.z, a4.w};
            float b[4] = {b4.x, b4.y, b4.z, b4.w};
            for (int ar = 0; ar < 4; ++ar)
                for (int bc = 0; bc < 4; ++bc)
                    acc[ar][bc] += a[ar] * b[bc];
        }
        __syncthreads();
    }
    for (int ar = 0; ar < 4; ++ar) {
        float4 o = make_float4(acc[ar][0], acc[ar][1], acc[ar][2], acc[ar][3]);
        *(float4*)&out[(size_t)(i0 + tr * 4 + ar) * KK + k0 + tc * 4] = o;
    }
}

extern "C" void kernel_launch(void* const* d_in, const int* in_sizes, int n_in,
                              void* d_out, int out_size, void* d_ws, size_t ws_size,
                              hipStream_t stream) {
    const float* x  = (const float*)d_in[0];   // [N*D]
    const float* V0 = (const float*)d_in[1];   // [D*K]
    float* out = (float*)d_out;                // [N*K]

    float* G    = (float*)d_ws;                // D*D
    float* V0T  = G + (size_t)DD * DD;         // K*D
    float* Vn   = V0T + (size_t)KK * DD;       // K*D
    float* gbuf = Vn + (size_t)KK * DD;        // 2*D (double-buffered g)
    float* wbuf = gbuf + 2 * DD;               // 2*D (double-buffered w)
    float* d0   = wbuf + 2 * DD;               // K
    unsigned* bar = (unsigned*)(d0 + KK);      // tree barrier: 2176 words

    ktranspose<<<dim3(DD / 32, KK / 32), 256, 0, stream>>>(V0, V0T);
    kd0<<<KK, 256, 0, stream>>>(V0T, d0);
    ksyrk<<<528, 256, 0, stream>>>(x, G);

    hipMemsetAsync(bar, 0, 2176 * sizeof(unsigned), stream);
    hipMemsetAsync(gbuf, 0, DD * sizeof(float), stream);   // g_{-1} = 0 (parity 0)

    void* kargs[] = {(void*)&G, (void*)&V0T, (void*)&d0, (void*)&Vn,
                     (void*)&gbuf, (void*)&wbuf, (void*)&bar};
    hipError_t cerr = hipLaunchCooperativeKernel(kloop2, dim3(NB), dim3(1024),
                                                 kargs, 0, stream);
    if (cerr != hipSuccess) {
        // fallback: original per-iteration launch loop (gbuf->g, wbuf->sbuf aliases)
        float* g = gbuf;
        float* sbuf = wbuf;
        kmatvecG<<<512, 256, 0, stream>>>(G, V0T, sbuf);
        for (int k = 0; k < KK; ++k) {
            float* s_cur = sbuf + (k & 1) * DD;
            float* s_nxt = sbuf + ((k + 1) & 1) * DD;
            kstep1<<<512, 256, 0, stream>>>(G, V0T, d0, s_cur, g, Vn, k);
            if (k < KK - 1)
                kstep2<<<512, 256, 0, stream>>>(G, V0T, Vn, g, s_nxt, k, k + 1);
        }
    }

    kout<<<dim3(NN / 64, KK / 64), 256, 0, stream>>>(x, Vn, out);
}